// Round 1
// baseline (27695.178 us; speedup 1.0000x reference)
//
#include <hip/hip_runtime.h>
#include <math.h>

// Problem constants
#define SEQ 512
#define BAT 32
#define HID 512
#define NG  3072   // 4H (gates) + H (r) + H (xl)
#define CH  16     // time chunk for the input-projection GEMM

// ---------------------------------------------------------------------------
// zero init
__global__ void zero_kernel(float* __restrict__ p, int n) {
    int i = blockIdx.x * 256 + threadIdx.x;
    if (i < n) p[i] = 0.f;
}

// ---------------------------------------------------------------------------
// Input projection GEMM (fp32, NT):
//   P[m][n] = sum_k A[m][k] * W[n][k] + bias[n]
// A row m -> (t_local = m/32, b = m%32), logical t = t0 + t_local,
// physical row = rev ? (511 - t) : t.
// W rows: n<2048 -> Wih[n]; n<2560 -> Wgi[n-2048]; else Wli[n-2560]
// bias:   n<2048 -> bih[n]+bhh[n]; n<2560 -> bgi[.]+bgs[.]; else 0
#define BM 64
#define BN 64
#define BK 32
__global__ __launch_bounds__(256) void proj_gemm(
    const float* __restrict__ xin, int t0, int rev,
    const float* __restrict__ Wih, const float* __restrict__ Wgi,
    const float* __restrict__ Wli,
    const float* __restrict__ bih, const float* __restrict__ bhh,
    const float* __restrict__ bgi, const float* __restrict__ bgs,
    float* __restrict__ P)
{
    __shared__ float As[BK][BM + 4];  // [k][m], stride 68 floats (16B aligned)
    __shared__ float Bs[BK][BN + 4];

    const int tid = threadIdx.x;
    const int bm = blockIdx.x;        // M tile (CH*32/64 tiles)
    const int bn = blockIdx.y;        // N tile (48 tiles)
    const int tx = tid & 15;          // n micro
    const int ty = tid >> 4;          // m micro

    float acc[4][4];
#pragma unroll
    for (int i = 0; i < 4; i++)
#pragma unroll
        for (int j = 0; j < 4; j++) acc[i][j] = 0.f;

    for (int k0 = 0; k0 < HID; k0 += BK) {
        // load A tile: 64 rows x 32 k = 512 float4, 2 per thread
#pragma unroll
        for (int i = 0; i < 2; i++) {
            int f = tid + i * 256;          // 0..511
            int m = f >> 3, kq = f & 7;     // m 0..63, kq 0..7
            int gm = bm * 64 + m;           // row within chunk [0, CH*32)
            int t = t0 + (gm >> 5), b = gm & 31;
            int pt = rev ? (SEQ - 1 - t) : t;
            const float* ap = xin + ((size_t)pt * BAT + b) * HID + k0 + kq * 4;
            float4 a4 = *(const float4*)ap;
            As[kq * 4 + 0][m] = a4.x;
            As[kq * 4 + 1][m] = a4.y;
            As[kq * 4 + 2][m] = a4.z;
            As[kq * 4 + 3][m] = a4.w;
        }
        // load B tile: 64 rows x 32 k
#pragma unroll
        for (int i = 0; i < 2; i++) {
            int f = tid + i * 256;
            int n = f >> 3, kq = f & 7;
            int gn = bn * 64 + n;
            const float* wrow = (gn < 2048) ? (Wih + (size_t)gn * HID)
                              : (gn < 2560) ? (Wgi + (size_t)(gn - 2048) * HID)
                                            : (Wli + (size_t)(gn - 2560) * HID);
            float4 b4 = *(const float4*)(wrow + k0 + kq * 4);
            Bs[kq * 4 + 0][n] = b4.x;
            Bs[kq * 4 + 1][n] = b4.y;
            Bs[kq * 4 + 2][n] = b4.z;
            Bs[kq * 4 + 3][n] = b4.w;
        }
        __syncthreads();
#pragma unroll
        for (int k = 0; k < BK; k++) {
            float4 a4 = *(const float4*)&As[k][ty * 4];
            float4 b4 = *(const float4*)&Bs[k][tx * 4];
            float a[4] = {a4.x, a4.y, a4.z, a4.w};
            float b[4] = {b4.x, b4.y, b4.z, b4.w};
#pragma unroll
            for (int i = 0; i < 4; i++)
#pragma unroll
                for (int j = 0; j < 4; j++) acc[i][j] += a[i] * b[j];
        }
        __syncthreads();
    }

    // epilogue: add fused bias, store
    int gnb = bn * 64 + tx * 4;
    float bias[4];
#pragma unroll
    for (int j = 0; j < 4; j++) {
        int gn = gnb + j;
        bias[j] = (gn < 2048) ? (bih[gn] + bhh[gn])
                : (gn < 2560) ? (bgi[gn - 2048] + bgs[gn - 2048])
                              : 0.f;
    }
#pragma unroll
    for (int i = 0; i < 4; i++) {
        int m = bm * 64 + ty * 4 + i;   // chunk-local row
        float4 o;
        o.x = acc[i][0] + bias[0];
        o.y = acc[i][1] + bias[1];
        o.z = acc[i][2] + bias[2];
        o.w = acc[i][3] + bias[3];
        *(float4*)(P + (size_t)m * NG + gnb) = o;
    }
}

// ---------------------------------------------------------------------------
// One LSTM time step.
// grid: 64 blocks x 256 threads. Block owns 8 h-indices (all 5 gate rows
// each). thread = (b = tid%32, j = jbase + tid/32). Full K=512 dot per gate.
__device__ __forceinline__ float sigf(float x) { return 1.f / (1.f + expf(-x)); }

#define HS_STRIDE 516  // pad 512 -> 516 (16B aligned, 4-way instead of 32-way)

__global__ __launch_bounds__(256) void lstm_step(
    const float* __restrict__ Pt,     // [32][3072] for this t
    const float* __restrict__ Whh,    // [2048][512]
    const float* __restrict__ Wgs,    // [512][512]
    const float* __restrict__ Hin,    // [32][512]
    float* __restrict__ Hout,         // [32][512]
    float* __restrict__ Cbuf,         // [32][512] in-place
    const float* __restrict__ maskt,  // [32] (already offset to physical t)
    const float* __restrict__ dm,     // [32][512] layer drop mask
    float* __restrict__ obase,        // output base for this t
    int ostride,                      // per-batch stride in output
    const int* __restrict__ trainPtr)
{
    __shared__ float Hs[BAT * HS_STRIDE];
    const int tid = threadIdx.x;

    // stage H into LDS (coalesced float4)
    for (int f = tid; f < (BAT * HID) / 4; f += 256) {
        int b = f >> 7, kq = f & 127;
        *(float4*)&Hs[b * HS_STRIDE + kq * 4] = *(const float4*)(Hin + b * HID + kq * 4);
    }
    __syncthreads();

    const int b = tid & 31;
    const int j = blockIdx.x * 8 + (tid >> 5);

    const float4* w0 = (const float4*)(Whh + ((size_t)(0 * HID + j)) * HID);
    const float4* w1 = (const float4*)(Whh + ((size_t)(1 * HID + j)) * HID);
    const float4* w2 = (const float4*)(Whh + ((size_t)(2 * HID + j)) * HID);
    const float4* w3 = (const float4*)(Whh + ((size_t)(3 * HID + j)) * HID);
    const float4* w4 = (const float4*)(Wgs + (size_t)j * HID);
    const float4* hp = (const float4*)&Hs[b * HS_STRIDE];

    float ai = 0.f, af = 0.f, ag = 0.f, ao = 0.f, ar = 0.f;
#pragma unroll 4
    for (int k = 0; k < HID / 4; k++) {
        float4 h4 = hp[k];
        float4 x;
        x = w0[k]; ai += x.x * h4.x + x.y * h4.y + x.z * h4.z + x.w * h4.w;
        x = w1[k]; af += x.x * h4.x + x.y * h4.y + x.z * h4.z + x.w * h4.w;
        x = w2[k]; ag += x.x * h4.x + x.y * h4.y + x.z * h4.z + x.w * h4.w;
        x = w3[k]; ao += x.x * h4.x + x.y * h4.y + x.z * h4.z + x.w * h4.w;
        x = w4[k]; ar += x.x * h4.x + x.y * h4.y + x.z * h4.z + x.w * h4.w;
    }

    // epilogue: pointwise cell math
    const float* Pb = Pt + (size_t)b * NG;
    float pi = Pb[j];
    float pf = Pb[512 + j];
    float pg = Pb[1024 + j];
    float po = Pb[1536 + j];
    float pr = Pb[2048 + j];
    float xl = Pb[2560 + j];

    float c_old = Cbuf[b * HID + j];
    float h_old = Hs[b * HS_STRIDE + j];

    float ig = sigf(pi + ai);
    float fg = sigf(pf + af);
    float gg = tanhf(pg + ag);
    float og = sigf(po + ao);
    float ct = fg * c_old + ig * gg;
    float hr = og * tanhf(ct);
    float r  = sigf(pr + ar);
    float h2 = r * hr + (1.f - r) * xl;
    if (*trainPtr) h2 *= dm[b * HID + j];
    float m  = maskt[b];
    float hn = m * h2 + (1.f - m) * h_old;
    float cn = m * ct + (1.f - m) * c_old;

    Hout[b * HID + j] = hn;
    Cbuf[b * HID + j] = cn;
    obase[(size_t)b * ostride + j] = hn;
}

// ---------------------------------------------------------------------------
extern "C" void kernel_launch(void* const* d_in, const int* in_sizes, int n_in,
                              void* d_out, int out_size, void* d_ws, size_t ws_size,
                              hipStream_t stream) {
    const float* x        = (const float*)d_in[0];
    const float* mask     = (const float*)d_in[1];
    const float* W_ih     = (const float*)d_in[2];
    const float* b_ih     = (const float*)d_in[3];
    const float* W_hh     = (const float*)d_in[4];
    const float* b_hh     = (const float*)d_in[5];
    const float* Wg_in    = (const float*)d_in[6];
    const float* bg_in    = (const float*)d_in[7];
    const float* Wg_state = (const float*)d_in[8];
    const float* bg_state = (const float*)d_in[9];
    const float* Wl_in    = (const float*)d_in[10];
    const float* drop     = (const float*)d_in[11];
    const int*   train    = (const int*)d_in[12];
    float* out = (float*)d_out;

    // workspace layout (floats):
    //   P     : CH*32*3072          = 1,572,864  (6.3 MB)
    //   Y     : 512*32*512          = 8,388,608  (33.6 MB) layer-0 output
    //   Hbuf  : 2*32*512            = 32,768
    //   Cbuf  : 32*512              = 16,384
    float* P    = (float*)d_ws;
    float* Y    = P + (size_t)CH * BAT * NG;
    float* Hbuf = Y + (size_t)SEQ * BAT * HID;
    float* Cbuf = Hbuf + 2 * BAT * HID;

    for (int l = 0; l < 2; l++) {
        const float* xin = l ? Y : x;
        const int rev = l;
        const float* Wih = W_ih + (size_t)l * 4 * HID * HID;
        const float* Whh = W_hh + (size_t)l * 4 * HID * HID;
        const float* Wgi = Wg_in + (size_t)l * HID * HID;
        const float* Wli = Wl_in + (size_t)l * HID * HID;
        const float* bih = b_ih + (size_t)l * 4 * HID;
        const float* bhh = b_hh + (size_t)l * 4 * HID;
        const float* bgi = bg_in + (size_t)l * HID;
        const float* dm  = drop + (size_t)l * BAT * HID;

        // zero h(both buffers) and c
        zero_kernel<<<(3 * BAT * HID + 255) / 256, 256, 0, stream>>>(Hbuf, 3 * BAT * HID);

        for (int c = 0; c < SEQ / CH; c++) {
            const int t0 = c * CH;
            proj_gemm<<<dim3((CH * BAT) / BM, NG / BN), 256, 0, stream>>>(
                xin, t0, rev, Wih, Wgi, Wli, bih, bhh, bgi, bg_state, P);
            for (int tl = 0; tl < CH; tl++) {
                const int t = t0 + tl;
                const float* Pt = P + (size_t)tl * BAT * NG;
                float* Hin  = Hbuf + (size_t)(t & 1) * BAT * HID;
                float* Hout = Hbuf + (size_t)((t + 1) & 1) * BAT * HID;
                const int tPhys = rev ? (SEQ - 1 - t) : t;
                float* obase;
                int ostride;
                if (l == 0) { obase = Y + (size_t)t * BAT * HID; ostride = HID; }
                else        { obase = out + (size_t)(SEQ - 1 - t) * HID; ostride = SEQ * HID; }
                lstm_step<<<HID / 8, 256, 0, stream>>>(
                    Pt, Whh, Wg_state, Hin, Hout, Cbuf,
                    mask + (size_t)tPhys * BAT, dm, obase, ostride, train);
            }
        }
    }
}

// Round 2
// 12944.629 us; speedup vs baseline: 2.1395x; 2.1395x over previous
//
#include <hip/hip_runtime.h>
#include <math.h>

#define SEQ 512
#define BAT 32
#define HID 512
#define NG  3072   // 4H gates + H (r) + H (xl)
#define CH  16     // time chunk
#define NB  64     // scan blocks (8 units each)
#define LSTR 520   // LDS row stride in bf16 elements (pad 512+8)

typedef __attribute__((ext_vector_type(8))) short bfrag;
typedef __attribute__((ext_vector_type(4))) float f32x4;

__device__ __forceinline__ float sigf(float x) { return 1.f / (1.f + expf(-x)); }

__device__ __forceinline__ unsigned short f2bf(float x) {
    unsigned u = __float_as_uint(x);
    unsigned r = (u + 0x7fffu + ((u >> 16) & 1u)) >> 16;
    return (unsigned short)r;
}

// ---------------------------------------------------------------------------
// Input projection GEMM (fp32, NT) — unchanged from round 0 (verified).
#define BM 64
#define BN 64
#define BK 32
__global__ __launch_bounds__(256) void proj_gemm(
    const float* __restrict__ xin, int t0, int rev,
    const float* __restrict__ Wih, const float* __restrict__ Wgi,
    const float* __restrict__ Wli,
    const float* __restrict__ bih, const float* __restrict__ bhh,
    const float* __restrict__ bgi, const float* __restrict__ bgs,
    float* __restrict__ P)
{
    __shared__ float As[BK][BM + 4];
    __shared__ float Bs[BK][BN + 4];

    const int tid = threadIdx.x;
    const int bm = blockIdx.x;
    const int bn = blockIdx.y;
    const int tx = tid & 15;
    const int ty = tid >> 4;

    float acc[4][4];
#pragma unroll
    for (int i = 0; i < 4; i++)
#pragma unroll
        for (int j = 0; j < 4; j++) acc[i][j] = 0.f;

    for (int k0 = 0; k0 < HID; k0 += BK) {
#pragma unroll
        for (int i = 0; i < 2; i++) {
            int f = tid + i * 256;
            int m = f >> 3, kq = f & 7;
            int gm = bm * 64 + m;
            int t = t0 + (gm >> 5), b = gm & 31;
            int pt = rev ? (SEQ - 1 - t) : t;
            const float* ap = xin + ((size_t)pt * BAT + b) * HID + k0 + kq * 4;
            float4 a4 = *(const float4*)ap;
            As[kq * 4 + 0][m] = a4.x;
            As[kq * 4 + 1][m] = a4.y;
            As[kq * 4 + 2][m] = a4.z;
            As[kq * 4 + 3][m] = a4.w;
        }
#pragma unroll
        for (int i = 0; i < 2; i++) {
            int f = tid + i * 256;
            int n = f >> 3, kq = f & 7;
            int gn = bn * 64 + n;
            const float* wrow = (gn < 2048) ? (Wih + (size_t)gn * HID)
                              : (gn < 2560) ? (Wgi + (size_t)(gn - 2048) * HID)
                                            : (Wli + (size_t)(gn - 2560) * HID);
            float4 b4 = *(const float4*)(wrow + k0 + kq * 4);
            Bs[kq * 4 + 0][n] = b4.x;
            Bs[kq * 4 + 1][n] = b4.y;
            Bs[kq * 4 + 2][n] = b4.z;
            Bs[kq * 4 + 3][n] = b4.w;
        }
        __syncthreads();
#pragma unroll
        for (int k = 0; k < BK; k++) {
            float4 a4 = *(const float4*)&As[k][ty * 4];
            float4 b4 = *(const float4*)&Bs[k][tx * 4];
            float a[4] = {a4.x, a4.y, a4.z, a4.w};
            float b[4] = {b4.x, b4.y, b4.z, b4.w};
#pragma unroll
            for (int i = 0; i < 4; i++)
#pragma unroll
                for (int j = 0; j < 4; j++) acc[i][j] += a[i] * b[j];
        }
        __syncthreads();
    }

    int gnb = bn * 64 + tx * 4;
    float bias[4];
#pragma unroll
    for (int j = 0; j < 4; j++) {
        int gn = gnb + j;
        bias[j] = (gn < 2048) ? (bih[gn] + bhh[gn])
                : (gn < 2560) ? (bgi[gn - 2048] + bgs[gn - 2048])
                              : 0.f;
    }
#pragma unroll
    for (int i = 0; i < 4; i++) {
        int m = bm * 64 + ty * 4 + i;
        float4 o;
        o.x = acc[i][0] + bias[0];
        o.y = acc[i][1] + bias[1];
        o.z = acc[i][2] + bias[2];
        o.w = acc[i][3] + bias[3];
        *(float4*)(P + (size_t)m * NG + gnb) = o;
    }
}

// ---------------------------------------------------------------------------
// Persistent scan over CH steps. 64 blocks x 256 threads, 1 block/CU.
// Block owns 8 hidden units: 40 weight rows (gates-major: g*8+ul, r: 32+ul)
// staged once as bf16 in LDS. Per step: stage h (bf16, parity buffer) ->
// MFMA 32x48x512 -> pointwise fp32 -> write h/y -> device flag barrier.
__global__ __launch_bounds__(256) void scan_chunk(
    const float* __restrict__ P,      // [CH][32][3072]
    const float* __restrict__ Whh,    // [2048][512]
    const float* __restrict__ Wgs,    // [512][512]
    unsigned short* __restrict__ Hbf, // [2][32][512] bf16
    float* __restrict__ Hf32,         // [32][512]
    float* __restrict__ Cbuf,         // [32][512]
    const float* __restrict__ mask,   // [512][32]
    const float* __restrict__ dm,     // [32][512]
    float* __restrict__ Y,            // layer0 out [512][32][512]
    float* __restrict__ out,          // final out [32][512][512]
    int l, int c,
    const int* __restrict__ trainPtr,
    unsigned* __restrict__ cnt)
{
    __shared__ unsigned short w_lds[48 * LSTR]; // 49,920 B
    __shared__ unsigned short h_lds[32 * LSTR]; // 33,280 B
    __shared__ float Dst[32 * 49];              //  6,272 B

    const int tid = threadIdx.x;
    const int u0 = blockIdx.x * 8;
    const int b = tid & 31;
    const int ul = tid >> 5;
    const int u = u0 + ul;
    const int lane = tid & 63;
    const int wv = tid >> 6;
    const int rev = (l == 1);

    // --- stage weights (once per chunk): 40 rows fp32 -> bf16 LDS
    for (int f = tid; f < 40 * 128; f += 256) {
        int r = f >> 7, kq = f & 127;
        int g = r >> 3, uu = u0 + (r & 7);
        const float* src = (g < 4) ? (Whh + ((size_t)(g * 512 + uu)) * 512)
                                   : (Wgs + (size_t)uu * 512);
        float4 v = *(const float4*)(src + kq * 4);
        uint2 pk;
        pk.x = (unsigned)f2bf(v.x) | ((unsigned)f2bf(v.y) << 16);
        pk.y = (unsigned)f2bf(v.z) | ((unsigned)f2bf(v.w) << 16);
        *(uint2*)&w_lds[r * LSTR + kq * 4] = pk;
    }
    // zero pad rows 40..47 (read by N-tile 2, never consumed)
    for (int f = tid; f < (8 * LSTR) / 2; f += 256)
        ((unsigned*)&w_lds[40 * LSTR])[f] = 0u;

    // --- persistent per-thread state: thread = (b, ul)
    float h_reg = Hf32[b * HID + u];
    float c_reg = Cbuf[b * HID + u];
    const int train = *trainPtr;
    const float dmv = train ? dm[b * HID + u] : 1.0f;

    // MFMA tile assignment per wave: (mt,nt) pairs over 2x3 tiles
    const int MT0[4] = {0, 0, 0, 1}, NT0[4] = {0, 1, 2, 0};
    const int MT1[4] = {1, 1, -1, -1}, NT1[4] = {1, 2, -1, -1};
    const int koff = (lane >> 4) * 8;
    const int row15 = lane & 15;

    __syncthreads();

    for (int s = 0; s < CH; s++) {
        const int t = c * CH + s;
        const int p = t & 1;
        const int tPhys = rev ? (SEQ - 1 - t) : t;

        // stage h_{t-1} (bf16) -> LDS, coalesced 16B chunks
        for (int f = tid; f < 2048; f += 256) {
            int bb = f >> 6, k16 = f & 63;
            uint4 v = *(const uint4*)(Hbf + (size_t)p * (BAT * HID) + bb * HID + k16 * 8);
            *(uint4*)&h_lds[bb * LSTR + k16 * 8] = v;
        }
        // issue P / mask loads early (independent of h)
        const float* Pb = P + ((size_t)s * BAT + b) * NG;
        float pv_i = Pb[u];
        float pv_f = Pb[512 + u];
        float pv_g = Pb[1024 + u];
        float pv_o = Pb[1536 + u];
        float pv_r = Pb[2048 + u];
        float xlv  = Pb[2560 + u];
        float mk   = mask[(size_t)tPhys * BAT + b];
        __syncthreads();

        // --- MFMA: D[b][n] = sum_k h[b][k] * w[n][k]
        f32x4 acc0 = {0.f, 0.f, 0.f, 0.f};
        f32x4 acc1 = {0.f, 0.f, 0.f, 0.f};
        {
            const unsigned short* ha0 = &h_lds[(MT0[wv] * 16 + row15) * LSTR + koff];
            const unsigned short* wb0 = &w_lds[(NT0[wv] * 16 + row15) * LSTR + koff];
            const int has1 = (wv < 2);
            const unsigned short* ha1 = has1 ? &h_lds[(MT1[wv] * 16 + row15) * LSTR + koff] : ha0;
            const unsigned short* wb1 = has1 ? &w_lds[(NT1[wv] * 16 + row15) * LSTR + koff] : wb0;
#pragma unroll
            for (int ks = 0; ks < 16; ks++) {
                bfrag a0 = *(const bfrag*)(ha0 + ks * 32);
                bfrag b0 = *(const bfrag*)(wb0 + ks * 32);
                acc0 = __builtin_amdgcn_mfma_f32_16x16x32_bf16(a0, b0, acc0, 0, 0, 0);
                if (has1) {
                    bfrag a1 = *(const bfrag*)(ha1 + ks * 32);
                    bfrag b1 = *(const bfrag*)(wb1 + ks * 32);
                    acc1 = __builtin_amdgcn_mfma_f32_16x16x32_bf16(a1, b1, acc1, 0, 0, 0);
                }
            }
            // D layout: row(m) = (lane>>4)*4 + r, col(n) = lane&15
            int col0 = NT0[wv] * 16 + row15;
            int mr0 = MT0[wv] * 16 + (lane >> 4) * 4;
#pragma unroll
            for (int r = 0; r < 4; r++) Dst[(mr0 + r) * 49 + col0] = acc0[r];
            if (has1) {
                int col1 = NT1[wv] * 16 + row15;
                int mr1 = MT1[wv] * 16 + (lane >> 4) * 4;
#pragma unroll
                for (int r = 0; r < 4; r++) Dst[(mr1 + r) * 49 + col1] = acc1[r];
            }
        }
        __syncthreads();

        // --- pointwise (fp32): thread (b, ul)
        float gi = sigf(pv_i + Dst[b * 49 + ul]);
        float gf = sigf(pv_f + Dst[b * 49 + 8 + ul]);
        float gg = tanhf(pv_g + Dst[b * 49 + 16 + ul]);
        float go = sigf(pv_o + Dst[b * 49 + 24 + ul]);
        float gr = sigf(pv_r + Dst[b * 49 + 32 + ul]);
        float ct = gf * c_reg + gi * gg;
        float hr_ = go * tanhf(ct);
        float h2 = gr * hr_ + (1.f - gr) * xlv;
        h2 *= dmv;
        float hn = mk * h2 + (1.f - mk) * h_reg;
        float cn = mk * ct + (1.f - mk) * c_reg;
        h_reg = hn;
        c_reg = cn;

        // publish h (next parity) + output y
        Hbf[(size_t)(p ^ 1) * (BAT * HID) + b * HID + u] = f2bf(hn);
        if (l == 0) Y[(size_t)t * BAT * HID + b * HID + u] = hn;
        else        out[(size_t)b * SEQ * HID + (size_t)(SEQ - 1 - t) * HID + u] = hn;

        // --- device-scope barrier (skip after last step; kernel boundary syncs)
        if (s != CH - 1) {
            __syncthreads();
            if (tid == 0) {
                __threadfence();
                __hip_atomic_fetch_add(cnt, 1u, __ATOMIC_RELEASE, __HIP_MEMORY_SCOPE_AGENT);
                unsigned target = (unsigned)NB * ((unsigned)((l * 32 + c) * (CH - 1) + s + 1));
                while (__hip_atomic_load(cnt, __ATOMIC_ACQUIRE, __HIP_MEMORY_SCOPE_AGENT) < target)
                    __builtin_amdgcn_s_sleep(1);
                __threadfence();
            }
            __syncthreads();
        }
    }

    // persist state for next chunk
    Hf32[b * HID + u] = h_reg;
    Cbuf[b * HID + u] = c_reg;
}

// ---------------------------------------------------------------------------
extern "C" void kernel_launch(void* const* d_in, const int* in_sizes, int n_in,
                              void* d_out, int out_size, void* d_ws, size_t ws_size,
                              hipStream_t stream) {
    const float* x        = (const float*)d_in[0];
    const float* mask     = (const float*)d_in[1];
    const float* W_ih     = (const float*)d_in[2];
    const float* b_ih     = (const float*)d_in[3];
    const float* W_hh     = (const float*)d_in[4];
    const float* b_hh     = (const float*)d_in[5];
    const float* Wg_in    = (const float*)d_in[6];
    const float* bg_in    = (const float*)d_in[7];
    const float* Wg_state = (const float*)d_in[8];
    const float* bg_state = (const float*)d_in[9];
    const float* Wl_in    = (const float*)d_in[10];
    const float* drop     = (const float*)d_in[11];
    const int*   train    = (const int*)d_in[12];
    float* out = (float*)d_out;

    // ws layout (float units):
    //   P    : CH*32*3072   = 1,572,864
    //   Y    : 512*32*512   = 8,388,608
    //   Hbf  : 2*32*512 bf16 = 16,384 float-equiv
    //   Hf32 : 32*512       = 16,384
    //   Cbuf : 32*512       = 16,384
    //   cnt  : 16
    float* P    = (float*)d_ws;
    float* Y    = P + (size_t)CH * BAT * NG;
    unsigned short* Hbf = (unsigned short*)(Y + (size_t)SEQ * BAT * HID);
    float* Hf32 = (float*)(Hbf + 2 * BAT * HID);
    float* Cbuf = Hf32 + BAT * HID;
    unsigned* cnt = (unsigned*)(Cbuf + BAT * HID);

    hipMemsetAsync(cnt, 0, 4, stream);

    for (int l = 0; l < 2; l++) {
        const int rev = l;
        const float* Wih = W_ih + (size_t)l * 4 * HID * HID;
        const float* Whh = W_hh + (size_t)l * 4 * HID * HID;
        const float* Wgi = Wg_in + (size_t)l * HID * HID;
        const float* Wli = Wl_in + (size_t)l * HID * HID;
        const float* bih = b_ih + (size_t)l * 4 * HID;
        const float* bhh = b_hh + (size_t)l * 4 * HID;
        const float* bgi = bg_in + (size_t)l * HID;
        const float* dm  = drop + (size_t)l * BAT * HID;
        const float* xin = l ? Y : x;

        // zero Hbf (both parities) + Hf32 + Cbuf in one memset (contiguous)
        hipMemsetAsync(Hbf, 0, (size_t)(2 * BAT * HID) * 2 + (size_t)(2 * BAT * HID) * 4, stream);

        for (int c = 0; c < SEQ / CH; c++) {
            proj_gemm<<<dim3((CH * BAT) / BM, NG / BN), 256, 0, stream>>>(
                xin, c * CH, rev, Wih, Wgi, Wli, bih, bhh, bgi, bg_state, P);
            scan_chunk<<<NB, 256, 0, stream>>>(
                P, Whh, Wg_state, Hbf, Hf32, Cbuf, mask, dm, Y, out,
                l, c, train, cnt);
        }
    }
}

// Round 3
// 7678.769 us; speedup vs baseline: 3.6067x; 1.6858x over previous
//
#include <hip/hip_runtime.h>
#include <math.h>

#define SEQ 512
#define BAT 32
#define HID 512
#define NG  3072   // 4H gates + H (r) + H (xl)
#define CH  32     // time chunk
#define NB  32     // scan blocks (16 units each)
#define UPB 16     // units per block
#define NW  80     // weight rows per block (5 gates x 16 units)
#define LSTR 520   // LDS row stride in bf16 elements
#define DSTR 81    // Dst row stride (floats)

typedef __attribute__((ext_vector_type(8))) short bfrag;
typedef __attribute__((ext_vector_type(4))) float f32x4;
typedef unsigned long long u64;

__device__ __forceinline__ float sigf(float x) { return 1.f / (1.f + expf(-x)); }

__device__ __forceinline__ unsigned short f2bf(float x) {
    unsigned u = __float_as_uint(x);
    unsigned r = (u + 0x7fffu + ((u >> 16) & 1u)) >> 16;
    return (unsigned short)r;
}

// ---------------------------------------------------------------------------
// Input projection GEMM (fp32, NT) — unchanged (verified round 0/1).
#define BM 64
#define BN 64
#define BK 32
__global__ __launch_bounds__(256) void proj_gemm(
    const float* __restrict__ xin, int t0, int rev,
    const float* __restrict__ Wih, const float* __restrict__ Wgi,
    const float* __restrict__ Wli,
    const float* __restrict__ bih, const float* __restrict__ bhh,
    const float* __restrict__ bgi, const float* __restrict__ bgs,
    float* __restrict__ P)
{
    __shared__ float As[BK][BM + 4];
    __shared__ float Bs[BK][BN + 4];

    const int tid = threadIdx.x;
    const int bm = blockIdx.x;
    const int bn = blockIdx.y;
    const int tx = tid & 15;
    const int ty = tid >> 4;

    float acc[4][4];
#pragma unroll
    for (int i = 0; i < 4; i++)
#pragma unroll
        for (int j = 0; j < 4; j++) acc[i][j] = 0.f;

    for (int k0 = 0; k0 < HID; k0 += BK) {
#pragma unroll
        for (int i = 0; i < 2; i++) {
            int f = tid + i * 256;
            int m = f >> 3, kq = f & 7;
            int gm = bm * 64 + m;
            int t = t0 + (gm >> 5), b = gm & 31;
            int pt = rev ? (SEQ - 1 - t) : t;
            const float* ap = xin + ((size_t)pt * BAT + b) * HID + k0 + kq * 4;
            float4 a4 = *(const float4*)ap;
            As[kq * 4 + 0][m] = a4.x;
            As[kq * 4 + 1][m] = a4.y;
            As[kq * 4 + 2][m] = a4.z;
            As[kq * 4 + 3][m] = a4.w;
        }
#pragma unroll
        for (int i = 0; i < 2; i++) {
            int f = tid + i * 256;
            int n = f >> 3, kq = f & 7;
            int gn = bn * 64 + n;
            const float* wrow = (gn < 2048) ? (Wih + (size_t)gn * HID)
                              : (gn < 2560) ? (Wgi + (size_t)(gn - 2048) * HID)
                                            : (Wli + (size_t)(gn - 2560) * HID);
            float4 b4 = *(const float4*)(wrow + k0 + kq * 4);
            Bs[kq * 4 + 0][n] = b4.x;
            Bs[kq * 4 + 1][n] = b4.y;
            Bs[kq * 4 + 2][n] = b4.z;
            Bs[kq * 4 + 3][n] = b4.w;
        }
        __syncthreads();
#pragma unroll
        for (int k = 0; k < BK; k++) {
            float4 a4 = *(const float4*)&As[k][ty * 4];
            float4 b4 = *(const float4*)&Bs[k][tx * 4];
            float a[4] = {a4.x, a4.y, a4.z, a4.w};
            float b[4] = {b4.x, b4.y, b4.z, b4.w};
#pragma unroll
            for (int i = 0; i < 4; i++)
#pragma unroll
                for (int j = 0; j < 4; j++) acc[i][j] += a[i] * b[j];
        }
        __syncthreads();
    }

    int gnb = bn * 64 + tx * 4;
    float bias[4];
#pragma unroll
    for (int j = 0; j < 4; j++) {
        int gn = gnb + j;
        bias[j] = (gn < 2048) ? (bih[gn] + bhh[gn])
                : (gn < 2560) ? (bgi[gn - 2048] + bgs[gn - 2048])
                              : 0.f;
    }
#pragma unroll
    for (int i = 0; i < 4; i++) {
        int m = bm * 64 + ty * 4 + i;
        float4 o;
        o.x = acc[i][0] + bias[0];
        o.y = acc[i][1] + bias[1];
        o.z = acc[i][2] + bias[2];
        o.w = acc[i][3] + bias[3];
        *(float4*)(P + (size_t)m * NG + gnb) = o;
    }
}

// ---------------------------------------------------------------------------
// Persistent scan over CH steps. 32 blocks x 256 threads, 1 block/CU.
// Fence-free cross-block dataflow: h published as packed-bf16 u64 relaxed
// agent atomics (sc0 sc1 coherent), per-block flag array, no RMW, no
// buffer_inv / buffer_wbl2 anywhere in the step loop.
__global__ __launch_bounds__(256) void scan_chunk(
    const float* __restrict__ P,      // [CH][32][3072]
    const float* __restrict__ Whh,    // [2048][512]
    const float* __restrict__ Wgs,    // [512][512]
    u64* __restrict__ Hbf,            // [2][32][128] u64 (bf16 x4)
    float* __restrict__ Hf32,         // [32][512]
    float* __restrict__ Cbuf,         // [32][512]
    const float* __restrict__ mask,   // [512][32]
    const float* __restrict__ dm,     // [32][512]
    float* __restrict__ Y,            // layer0 out [512][32][512]
    float* __restrict__ out,          // final out [32][512][512]
    int l, int c,
    const int* __restrict__ trainPtr,
    unsigned* __restrict__ flags)     // [NB]
{
    __shared__ unsigned short w_lds[NW * LSTR];  // 83,200 B
    __shared__ unsigned short h_lds[BAT * LSTR]; // 33,280 B
    __shared__ float Dst[BAT * DSTR];            // 10,368 B
    __shared__ float hout[BAT * UPB];            //  2,048 B

    const int tid = threadIdx.x;
    const int u0 = blockIdx.x * UPB;
    const int b = tid & 31;
    const int ul = tid >> 5;          // 0..7
    const int lane = tid & 63;
    const int wv = tid >> 6;
    const int rev = (l == 1);
    const int row15 = lane & 15;
    const int koff = (lane >> 4) * 8;

    // --- stage weights once per chunk: 80 rows fp32 -> bf16 LDS
    // row r = g*16 + i  <->  g<4 ? Whh[g*512 + u0+i] : Wgs[u0+i]
    for (int f = tid; f < NW * 128; f += 256) {
        int r = f >> 7, kq = f & 127;
        int g = r >> 4, i = r & 15;
        const float* src = (g < 4) ? (Whh + ((size_t)(g * 512 + u0 + i)) * 512)
                                   : (Wgs + (size_t)(u0 + i) * 512);
        float4 v = *(const float4*)(src + kq * 4);
        uint2 pk;
        pk.x = (unsigned)f2bf(v.x) | ((unsigned)f2bf(v.y) << 16);
        pk.y = (unsigned)f2bf(v.z) | ((unsigned)f2bf(v.w) << 16);
        *(uint2*)&w_lds[r * LSTR + kq * 4] = pk;
    }

    // --- persistent per-thread state: (b, units u0+ul and u0+ul+8)
    const int i0u = ul, i1u = ul + 8;
    float h0 = Hf32[b * HID + u0 + i0u];
    float h1 = Hf32[b * HID + u0 + i1u];
    float c0 = Cbuf[b * HID + u0 + i0u];
    float c1 = Cbuf[b * HID + u0 + i1u];
    const int train = *trainPtr;
    const float dm0 = train ? dm[b * HID + u0 + i0u] : 1.0f;
    const float dm1 = train ? dm[b * HID + u0 + i1u] : 1.0f;

    const int base = (l * 16 + c) * (CH - 1);
    // MFMA tiles: idx = mt*5 + nt, 0..9; wave wv owns idx {wv, wv+4, wv+8(<10)}
    const int idx0 = wv, idx1 = wv + 4, idx2 = wv + 8;
    const int has2 = (wv < 2);

    for (int s = 0; s < CH; s++) {
        const int t = c * CH + s;
        const int p = t & 1;
        const int tPhys = rev ? (SEQ - 1 - t) : t;

        // --- prefetch P / mask (independent of h)
        const float* Pb = P + ((size_t)s * BAT + b) * NG;
        float pi0 = Pb[u0 + i0u],        pi1 = Pb[u0 + i1u];
        float pf0 = Pb[512 + u0 + i0u],  pf1 = Pb[512 + u0 + i1u];
        float pg0 = Pb[1024 + u0 + i0u], pg1 = Pb[1024 + u0 + i1u];
        float po0 = Pb[1536 + u0 + i0u], po1 = Pb[1536 + u0 + i1u];
        float pr0 = Pb[2048 + u0 + i0u], pr1 = Pb[2048 + u0 + i1u];
        float xl0 = Pb[2560 + u0 + i0u], xl1 = Pb[2560 + u0 + i1u];
        float mk  = mask[(size_t)tPhys * BAT + b];

        // --- wait for step-s h to be published (relaxed poll, no fences)
        if (s) {
            if (wv == 0) {
                const unsigned target = (unsigned)(base + s);
                unsigned v;
                do {
                    v = __hip_atomic_load(&flags[lane & (NB - 1)],
                                          __ATOMIC_RELAXED, __HIP_MEMORY_SCOPE_AGENT);
                } while (__any((int)(v < target)));
            }
            asm volatile("" ::: "memory");
        }
        __syncthreads();

        // --- gather h (coherent u64 loads, bypass L2) -> LDS bf16
        {
            const u64* Hsrc = Hbf + (size_t)p * (BAT * 128);
            u64 vals[16];
#pragma unroll
            for (int j = 0; j < 16; j++)
                vals[j] = __hip_atomic_load(&Hsrc[j * 256 + tid],
                                            __ATOMIC_RELAXED, __HIP_MEMORY_SCOPE_AGENT);
#pragma unroll
            for (int j = 0; j < 16; j++) {
                int f = j * 256 + tid;
                int bb = f >> 7, seg = f & 127;
                *(u64*)&h_lds[bb * LSTR + seg * 4] = vals[j];
            }
        }
        __syncthreads();

        // --- MFMA: D[b][n] = sum_k h[b][k] * w[n][k]
        {
            f32x4 a0 = {0.f,0.f,0.f,0.f}, a1 = {0.f,0.f,0.f,0.f}, a2 = {0.f,0.f,0.f,0.f};
            const unsigned short* ha0 = &h_lds[((idx0 / 5) * 16 + row15) * LSTR + koff];
            const unsigned short* wb0 = &w_lds[((idx0 % 5) * 16 + row15) * LSTR + koff];
            const unsigned short* ha1 = &h_lds[((idx1 / 5) * 16 + row15) * LSTR + koff];
            const unsigned short* wb1 = &w_lds[((idx1 % 5) * 16 + row15) * LSTR + koff];
            const unsigned short* ha2 = has2 ? &h_lds[((idx2 / 5) * 16 + row15) * LSTR + koff] : ha0;
            const unsigned short* wb2 = has2 ? &w_lds[((idx2 % 5) * 16 + row15) * LSTR + koff] : wb0;
#pragma unroll
            for (int ks = 0; ks < 16; ks++) {
                a0 = __builtin_amdgcn_mfma_f32_16x16x32_bf16(
                        *(const bfrag*)(ha0 + ks * 32), *(const bfrag*)(wb0 + ks * 32), a0, 0, 0, 0);
                a1 = __builtin_amdgcn_mfma_f32_16x16x32_bf16(
                        *(const bfrag*)(ha1 + ks * 32), *(const bfrag*)(wb1 + ks * 32), a1, 0, 0, 0);
                if (has2)
                    a2 = __builtin_amdgcn_mfma_f32_16x16x32_bf16(
                        *(const bfrag*)(ha2 + ks * 32), *(const bfrag*)(wb2 + ks * 32), a2, 0, 0, 0);
            }
            // D: m = mt*16 + (lane>>4)*4 + r (batch), n = nt*16 + row15
            {
                int mr = (idx0 / 5) * 16 + (lane >> 4) * 4, cl = (idx0 % 5) * 16 + row15;
#pragma unroll
                for (int r = 0; r < 4; r++) Dst[(mr + r) * DSTR + cl] = a0[r];
            }
            {
                int mr = (idx1 / 5) * 16 + (lane >> 4) * 4, cl = (idx1 % 5) * 16 + row15;
#pragma unroll
                for (int r = 0; r < 4; r++) Dst[(mr + r) * DSTR + cl] = a1[r];
            }
            if (has2) {
                int mr = (idx2 / 5) * 16 + (lane >> 4) * 4, cl = (idx2 % 5) * 16 + row15;
#pragma unroll
                for (int r = 0; r < 4; r++) Dst[(mr + r) * DSTR + cl] = a2[r];
            }
        }
        __syncthreads();

        // --- pointwise (fp32), 2 units per thread; gate g at rows g*16..+15
        float hn0, hn1;
        {
            float gi = sigf(pi0 + Dst[b * DSTR + 0  + i0u]);
            float gf = sigf(pf0 + Dst[b * DSTR + 16 + i0u]);
            float gg = tanhf(pg0 + Dst[b * DSTR + 32 + i0u]);
            float go = sigf(po0 + Dst[b * DSTR + 48 + i0u]);
            float gr = sigf(pr0 + Dst[b * DSTR + 64 + i0u]);
            float ct = gf * c0 + gi * gg;
            float hr_ = go * tanhf(ct);
            float h2 = (gr * hr_ + (1.f - gr) * xl0) * dm0;
            hn0 = mk * h2 + (1.f - mk) * h0;
            c0  = mk * ct + (1.f - mk) * c0;
            h0 = hn0;
        }
        {
            float gi = sigf(pi1 + Dst[b * DSTR + 0  + i1u]);
            float gf = sigf(pf1 + Dst[b * DSTR + 16 + i1u]);
            float gg = tanhf(pg1 + Dst[b * DSTR + 32 + i1u]);
            float go = sigf(po1 + Dst[b * DSTR + 48 + i1u]);
            float gr = sigf(pr1 + Dst[b * DSTR + 64 + i1u]);
            float ct = gf * c1 + gi * gg;
            float hr_ = go * tanhf(ct);
            float h2 = (gr * hr_ + (1.f - gr) * xl1) * dm1;
            hn1 = mk * h2 + (1.f - mk) * h1;
            c1  = mk * ct + (1.f - mk) * c1;
            h1 = hn1;
        }
        hout[b * UPB + i0u] = hn0;
        hout[b * UPB + i1u] = hn1;

        // outputs (plain stores; consumed across kernel boundaries only)
        if (l == 0) {
            Y[(size_t)t * BAT * HID + b * HID + u0 + i0u] = hn0;
            Y[(size_t)t * BAT * HID + b * HID + u0 + i1u] = hn1;
        } else {
            out[(size_t)b * SEQ * HID + (size_t)(SEQ - 1 - t) * HID + u0 + i0u] = hn0;
            out[(size_t)b * SEQ * HID + (size_t)(SEQ - 1 - t) * HID + u0 + i1u] = hn1;
        }
        __syncthreads();   // hout ready for packers

        // --- publish h (coherent u64 stores), then flag
        if (tid < 128) {
            int bb = tid >> 2, q = tid & 3;
            const float* hp = &hout[bb * UPB + q * 4];
            u64 v = (u64)f2bf(hp[0])
                  | ((u64)f2bf(hp[1]) << 16)
                  | ((u64)f2bf(hp[2]) << 32)
                  | ((u64)f2bf(hp[3]) << 48);
            __hip_atomic_store(&Hbf[(size_t)(p ^ 1) * (BAT * 128) + bb * 128 + (u0 >> 2) + q],
                               v, __ATOMIC_RELAXED, __HIP_MEMORY_SCOPE_AGENT);
        }
        if (s != CH - 1) {
            asm volatile("s_waitcnt vmcnt(0)" ::: "memory");
            __syncthreads();   // all waves' publishes complete
            if (tid == 0)
                __hip_atomic_store(&flags[blockIdx.x], (unsigned)(base + s + 1),
                                   __ATOMIC_RELAXED, __HIP_MEMORY_SCOPE_AGENT);
        }
    }

    // persist state for next chunk
    Hf32[b * HID + u0 + i0u] = h0;
    Hf32[b * HID + u0 + i1u] = h1;
    Cbuf[b * HID + u0 + i0u] = c0;
    Cbuf[b * HID + u0 + i1u] = c1;
}

// ---------------------------------------------------------------------------
extern "C" void kernel_launch(void* const* d_in, const int* in_sizes, int n_in,
                              void* d_out, int out_size, void* d_ws, size_t ws_size,
                              hipStream_t stream) {
    const float* x        = (const float*)d_in[0];
    const float* mask     = (const float*)d_in[1];
    const float* W_ih     = (const float*)d_in[2];
    const float* b_ih     = (const float*)d_in[3];
    const float* W_hh     = (const float*)d_in[4];
    const float* b_hh     = (const float*)d_in[5];
    const float* Wg_in    = (const float*)d_in[6];
    const float* bg_in    = (const float*)d_in[7];
    const float* Wg_state = (const float*)d_in[8];
    const float* bg_state = (const float*)d_in[9];
    const float* Wl_in    = (const float*)d_in[10];
    const float* drop     = (const float*)d_in[11];
    const int*   train    = (const int*)d_in[12];
    float* out = (float*)d_out;

    // ws layout:
    //   P     : CH*32*3072 fp32   = 12.58 MB
    //   Y     : 512*32*512 fp32   = 33.55 MB
    //   Hbf   : 2*32*128 u64      = 64 KB
    //   Hf32  : 32*512 fp32       = 64 KB
    //   Cbuf  : 32*512 fp32       = 64 KB
    //   flags : NB u32
    float* P    = (float*)d_ws;
    float* Y    = P + (size_t)CH * BAT * NG;
    u64*   Hbf  = (u64*)(Y + (size_t)SEQ * BAT * HID);
    float* Hf32 = (float*)(Hbf + 2 * BAT * 128);
    float* Cbuf = Hf32 + BAT * HID;
    unsigned* flags = (unsigned*)(Cbuf + BAT * HID);

    hipMemsetAsync(flags, 0, NB * sizeof(unsigned), stream);

    for (int l = 0; l < 2; l++) {
        const int rev = l;
        const float* Wih = W_ih + (size_t)l * 4 * HID * HID;
        const float* Whh = W_hh + (size_t)l * 4 * HID * HID;
        const float* Wgi = Wg_in + (size_t)l * HID * HID;
        const float* Wli = Wl_in + (size_t)l * HID * HID;
        const float* bih = b_ih + (size_t)l * 4 * HID;
        const float* bhh = b_hh + (size_t)l * 4 * HID;
        const float* bgi = bg_in + (size_t)l * HID;
        const float* dm  = drop + (size_t)l * BAT * HID;
        const float* xin = l ? Y : x;

        // zero Hbf (both parities) + Hf32 + Cbuf (contiguous 192 KB)
        hipMemsetAsync(Hbf, 0, (size_t)2 * BAT * 128 * 8 + (size_t)2 * BAT * HID * 4, stream);

        for (int c = 0; c < SEQ / CH; c++) {
            proj_gemm<<<dim3((CH * BAT) / BM, NG / BN), 256, 0, stream>>>(
                xin, c * CH, rev, Wih, Wgi, Wli, bih, bhh, bgi, bg_state, P);
            scan_chunk<<<NB, 256, 0, stream>>>(
                P, Whh, Wg_state, Hbf, Hf32, Cbuf, mask, dm, Y, out,
                l, c, train, flags);
        }
    }
}